// Round 5
// baseline (620.050 us; speedup 1.0000x reference)
//
#include <hip/hip_runtime.h>
#include <hip/hip_bf16.h>

using bf16 = __hip_bfloat16;
typedef __attribute__((ext_vector_type(8))) short short8;
typedef __attribute__((ext_vector_type(4))) float f32x4;

__device__ __forceinline__ float b2f(bf16 v){ return __bfloat162float(v); }
__device__ __forceinline__ float sigf(float v){ return 1.f/(1.f + __expf(-v)); }
__device__ __forceinline__ float ldv(const float* p, int i){ return p[i]; }
__device__ __forceinline__ float ldv(const bf16* p, int i){ return b2f(p[i]); }
__device__ __forceinline__ void stv(float* p, int i, float v){ p[i] = v; }
__device__ __forceinline__ void stv(bf16* p, int i, float v){ p[i] = __float2bfloat16(v); }
__device__ __forceinline__ unsigned short f2h(float v){
  bf16 h = __float2bfloat16(v); return *(unsigned short*)&h;
}
// 8 bf16 from 4-B-aligned LDS via 4x b32 (conflict-free with odd-word strides)
__device__ __forceinline__ short8 ld8u(const unsigned short* p){
  union { unsigned int u[4]; short8 s; } v;
  const unsigned int* q = (const unsigned int*)p;
  v.u[0] = q[0]; v.u[1] = q[1]; v.u[2] = q[2]; v.u[3] = q[3];
  return v.s;
}

// ---------------------------------------------------------------------------
// K0: dtype detect. flag=1 => inputs are f32.
// ---------------------------------------------------------------------------
__global__ __launch_bounds__(256) void k_detect(const unsigned short* xs, int* flag){
  __shared__ int cnt;
  if (threadIdx.x == 0) cnt = 0;
  __syncthreads();
  int local = 0;
  for (int i = threadIdx.x; i < 16384; i += 256){
    if (((xs[i] >> 7) & 0xFF) == 0xFF) local++;
  }
  if (local) atomicAdd(&cnt, local);
  __syncthreads();
  if (threadIdx.x == 0) *flag = (cnt > 0) ? 1 : 0;
}

// ---------------------------------------------------------------------------
// K0b: canonicalize params. 0-17: fp32 in cpar; 18: w_def->bf16;
// 19: w_off->bf16 pad 18->32 rows; 20: w_g1->bf16; 21: w_cross->bf16;
// 22: w_out->bf16. grid (96, 23).
// ---------------------------------------------------------------------------
struct ParamSrc { const void* p[18]; };

__global__ __launch_bounds__(256) void k_convert(ParamSrc ps, const int* flagp,
    float* cpar, bf16* wdefb, bf16* woffb, bf16* wg1b, bf16* wcrossb, bf16* woutb){
  static constexpr int n[23]   = {41472,18,147456,131072,147456,64,64,64,64,64,
                                  16384,256,65536,256,256,256,256,256,
                                  147456,73728,147456,131072,65536};
  static constexpr int off[18] = {0,41472,41504,188960,320032,467488,467552,467616,
                                  467680,467744,467808,484192,484448,549984,550240,
                                  550496,550752,551008};
  const int s = blockIdx.y;
  const bool f32 = (*flagp != 0);
  if (s >= 18){
    static constexpr int srcs[5] = {2, 0, 4, 3, 12};
    const int src_slot = srcs[s - 18];
    bf16* dsts[5] = {wdefb, woffb, wg1b, wcrossb, woutb};
    bf16* dst = dsts[s - 18];
    const int nsrc = (s == 19) ? 41472 : n[s];
    if (f32){
      const float* src = (const float*)ps.p[src_slot];
      for (int i = blockIdx.x * 256 + threadIdx.x; i < n[s]; i += gridDim.x * 256)
        dst[i] = (i < nsrc) ? __float2bfloat16(src[i]) : __float2bfloat16(0.f);
    } else {
      const bf16* src = (const bf16*)ps.p[src_slot];
      for (int i = blockIdx.x * 256 + threadIdx.x; i < n[s]; i += gridDim.x * 256)
        dst[i] = (i < nsrc) ? src[i] : __float2bfloat16(0.f);
    }
    return;
  }
  float* dst = cpar + off[s];
  if (f32){
    const float* src = (const float*)ps.p[s];
    for (int i = blockIdx.x * 256 + threadIdx.x; i < n[s]; i += gridDim.x * 256)
      dst[i] = src[i];
  } else {
    const bf16* src = (const bf16*)ps.p[s];
    for (int i = blockIdx.x * 256 + threadIdx.x; i < n[s]; i += gridDim.x * 256)
      dst[i] = b2f(src[i]);
  }
}

// ---------------------------------------------------------------------------
// Generic 3x3 pad=1 conv via im2col + MFMA (from R4, unchanged).
// ---------------------------------------------------------------------------
template<typename T, int COT, bool EPI>
__device__ __forceinline__ void conv3_body(const T* __restrict__ xin,
    const bf16* __restrict__ wb, const float* __restrict__ cbv,
    const float* __restrict__ gam, const float* __restrict__ bet,
    const float* __restrict__ mea, const float* __restrict__ var,
    float* __restrict__ outp, int co_lim, unsigned short* cols){
  const int bx = blockIdx.x;
  const int b = bx >> 6, y = bx & 63;
  const int t = threadIdx.x;
  const int l = t & 63, w = t >> 6;
  const int lm = l & 15, lq = l >> 4;
  const int pos2 = t & 31, kq = t >> 5;
  unsigned int* cols32 = (unsigned int*)cols;
  f32x4 acc[COT];
  #pragma unroll
  for (int m = 0; m < COT; m++) acc[m] = (f32x4){0.f,0.f,0.f,0.f};

  for (int cc = 0; cc < 256; cc += 32){
    __syncthreads();
    #pragma unroll
    for (int c8 = 0; c8 < 4; c8++){
      const int c_local = kq * 4 + c8;
      const T* xc = xin + (b * 256 + cc + c_local) * 4096;
      #pragma unroll
      for (int tap = 0; tap < 9; tap++){
        const int ti = tap / 3, tj = tap % 3;
        const int yy = y + ti - 1;
        const int px0 = 2 * pos2 + tj - 1;
        const bool vy = (unsigned)yy < 64u;
        float v0 = (vy && (unsigned)px0 < 64u) ? ldv(xc, yy * 64 + px0) : 0.f;
        float v1 = (vy && (unsigned)(px0 + 1) < 64u) ? ldv(xc, yy * 64 + px0 + 1) : 0.f;
        unsigned int packed = (unsigned int)f2h(v0) | ((unsigned int)f2h(v1) << 16);
        cols32[(c_local * 9 + tap) * 34 + pos2] = packed;
      }
    }
    __syncthreads();
    #pragma unroll
    for (int kk = 0; kk < 288; kk += 32){
      short8 bfr;
      #pragma unroll
      for (int j = 0; j < 8; j++)
        bfr[j] = (short)cols[(kk + lq * 8 + j) * 68 + w * 16 + lm];
      #pragma unroll
      for (int m = 0; m < COT; m++){
        const bf16* ap = wb + (m * 16 + lm) * 2304 + cc * 9 + kk + lq * 8;
        short8 afr = *(const short8*)ap;
        acc[m] = __builtin_amdgcn_mfma_f32_16x16x32_bf16(afr, bfr, acc[m], 0, 0, 0);
      }
    }
  }
  const int p = y * 64 + w * 16 + lm;
  #pragma unroll
  for (int m = 0; m < COT; m++){
    #pragma unroll
    for (int r = 0; r < 4; r++){
      const int co = m * 16 + lq * 4 + r;
      if (co >= co_lim) continue;
      float v = acc[m][r] + cbv[co];
      if constexpr (EPI){
        float inv = gam[co] * rsqrtf(var[co] + 1e-5f);
        v = v * inv + (bet[co] - mea[co] * inv);
        v = v * sigf(v);
      }
      outp[(b * co_lim + co) * 4096 + p] = v;
    }
  }
}

__global__ __launch_bounds__(256) void k_coff_m(const void* x, const int* flagp,
    const bf16* woffb, const float* cb, float* offc){
  __shared__ __align__(16) unsigned short cols[288 * 68];
  if (*flagp) conv3_body<float, 2, false>((const float*)x, woffb, cb,
                  nullptr, nullptr, nullptr, nullptr, offc, 18, cols);
  else        conv3_body<bf16, 2, false>((const bf16*)x, woffb, cb,
                  nullptr, nullptr, nullptr, nullptr, offc, 18, cols);
}

__global__ __launch_bounds__(256) void k_g1_m(const float* xdense,
    const bf16* wg1b, const float* cb, const float* gam, const float* bet,
    const float* mea, const float* var, float* abuf){
  __shared__ __align__(16) unsigned short cols[288 * 68];
  conv3_body<float, 4, true>(xdense, wg1b, cb, gam, bet, mea, var, abuf, 64, cols);
}

// ---------------------------------------------------------------------------
// K2: deformable conv, MFMA, K-chunked LDS (18.6 KB), conflict-free strides.
// Block = (group g, 32 px), grid (512, 4), 256 thr. Output bf16.
// cols row stride 290 u16 = 145 words (odd => all 32 banks).
// ---------------------------------------------------------------------------
#define CROW2 290

template<typename T>
__device__ __forceinline__ void deform_body(const T* __restrict__ x,
    const float* __restrict__ offc, const bf16* __restrict__ wdefb,
    unsigned short* __restrict__ xdirb, unsigned short* cols){
  const int g = blockIdx.y;
  const int q0 = blockIdx.x * 32;
  const int b = q0 >> 12, p0 = q0 & 4095;
  const int t = threadIdx.x;
  const int pos = t & 31, cslot = t >> 5;
  const int p = p0 + pos;
  const int y = p >> 6, xx = p & 63;
  const int w = t >> 6, l = t & 63, lrow = l & 15, lhi = l >> 4;
  float dyv[9], dxv[9];
  {
    const float* ob = offc + b * 18 * 4096 + p;
    #pragma unroll
    for (int k = 0; k < 9; k++){ dyv[k] = ob[(2*k)*4096]; dxv[k] = ob[(2*k+1)*4096]; }
  }
  f32x4 acc0 = {0.f,0.f,0.f,0.f}, acc1 = {0.f,0.f,0.f,0.f};
  #pragma unroll 1
  for (int cc = 0; cc < 2; cc++){
    __syncthreads();
    const T* xg = x + (((b*4 + g)*64) + cc*32) * 4096;
    #pragma unroll
    for (int k = 0; k < 9; k++){
      float py  = (float)(y + k/3 - 1) + dyv[k];
      float pxf = (float)(xx + k%3 - 1) + dxv[k];
      float y0f = floorf(py), x0f = floorf(pxf);
      int y0 = (int)y0f, x0 = (int)x0f;
      float wy1 = py - y0f, wx1 = pxf - x0f;
      float wy0 = 1.f - wy1, wx0 = 1.f - wx1;
      bool vy0 = (unsigned)y0 < 64u, vy1 = (unsigned)(y0+1) < 64u;
      bool vx0 = (unsigned)x0 < 64u, vx1 = (unsigned)(x0+1) < 64u;
      float w00 = (vy0 && vx0) ? wy0*wx0 : 0.f;
      float w01 = (vy0 && vx1) ? wy0*wx1 : 0.f;
      float w10 = (vy1 && vx0) ? wy1*wx0 : 0.f;
      float w11 = (vy1 && vx1) ? wy1*wx1 : 0.f;
      int yc0 = min(max(y0,0),63),   yc1 = min(max(y0+1,0),63);
      int xc0 = min(max(x0,0),63),   xc1 = min(max(x0+1,0),63);
      int i00 = yc0*64+xc0, i01 = yc0*64+xc1, i10 = yc1*64+xc0, i11 = yc1*64+xc1;
      #pragma unroll
      for (int j = 0; j < 4; j++){
        const int cl = cslot*4 + j;
        const T* xc = xg + cl*4096;
        float val = w00*ldv(xc,i00) + w01*ldv(xc,i01)
                  + w10*ldv(xc,i10) + w11*ldv(xc,i11);
        cols[pos*CROW2 + cl*9 + k] = f2h(val);
      }
    }
    __syncthreads();
    const bf16* wr = wdefb + (g*64 + w*16 + lrow)*576 + cc*288;
    const unsigned short* b0p = cols + lrow*CROW2;
    const unsigned short* b1p = cols + (16+lrow)*CROW2;
    #pragma unroll
    for (int kk = 0; kk < 288; kk += 32){
      const int ko = kk + lhi*8;
      short8 a  = *(const short8*)(wr + ko);
      short8 b0 = ld8u(b0p + ko);
      short8 b1 = ld8u(b1p + ko);
      acc0 = __builtin_amdgcn_mfma_f32_16x16x32_bf16(a, b0, acc0, 0, 0, 0);
      acc1 = __builtin_amdgcn_mfma_f32_16x16x32_bf16(a, b1, acc1, 0, 0, 0);
    }
  }
  const int co_base = g*64 + w*16 + lhi*4;
  #pragma unroll
  for (int r = 0; r < 4; r++){
    unsigned short* xo = xdirb + (b*256 + co_base + r)*4096 + p0 + lrow;
    xo[0]  = f2h(acc0[r]);
    xo[16] = f2h(acc1[r]);
  }
}

__global__ __launch_bounds__(256, 4) void k_deform(const void* x, const int* flagp,
    const float* offc, const bf16* wdefb, unsigned short* xdirb){
  __shared__ __align__(16) unsigned short cols[32 * CROW2];
  if (*flagp) deform_body((const float*)x, offc, wdefb, xdirb, cols);
  else        deform_body((const bf16*)x, offc, wdefb, xdirb, cols);
}

// ---------------------------------------------------------------------------
// K3: 1x1 conv concat([x_dir, x_prev]) * w_cross — MFMA GEMM.
// Block = 64 px x 64 co, grid (256, 4), 256 thr, 4 waves (wave = px-tile).
// B staged [px][66] u16 (33-word odd stride). A = bf16 weights from global.
// ---------------------------------------------------------------------------
template<typename T>
__device__ __forceinline__ void cross_body(const unsigned short* __restrict__ xdirb,
    const T* __restrict__ xprev, const bf16* __restrict__ wcb,
    float* __restrict__ xdense, unsigned short* bt){
  const int bx = blockIdx.x;
  const int b = bx >> 6, p0 = (bx & 63) * 64;
  const int co0 = blockIdx.y * 64;
  const int t = threadIdx.x;
  const int w = t >> 6, l = t & 63, lm = l & 15, lq = l >> 4;
  f32x4 acc[4];
  #pragma unroll
  for (int m = 0; m < 4; m++) acc[m] = (f32x4){0.f,0.f,0.f,0.f};
  for (int cc = 0; cc < 512; cc += 64){
    __syncthreads();
    // stage: wave w handles k = w*16..+16 for all 64 px (lane = px)
    #pragma unroll
    for (int j = 0; j < 16; j++){
      const int k = w * 16 + j;
      const int ci = cc + k;
      unsigned short hv;
      if (ci < 256) hv = xdirb[(b*256 + ci)*4096 + p0 + l];
      else          hv = f2h(ldv(xprev, (b*256 + ci - 256)*4096 + p0 + l));
      bt[l * 66 + k] = hv;
    }
    __syncthreads();
    #pragma unroll
    for (int ks = 0; ks < 2; ks++){
      short8 bfr = ld8u(bt + (w*16 + lm)*66 + ks*32 + lq*8);
      #pragma unroll
      for (int m = 0; m < 4; m++){
        short8 afr = *(const short8*)(wcb + (co0 + m*16 + lm)*512 + cc + ks*32 + lq*8);
        acc[m] = __builtin_amdgcn_mfma_f32_16x16x32_bf16(afr, bfr, acc[m], 0, 0, 0);
      }
    }
  }
  const int px = p0 + w*16 + lm;
  #pragma unroll
  for (int m = 0; m < 4; m++){
    #pragma unroll
    for (int r = 0; r < 4; r++)
      xdense[(b*256 + co0 + m*16 + lq*4 + r)*4096 + px] = acc[m][r];
  }
}

__global__ __launch_bounds__(256) void k_cross_m(const unsigned short* xdirb,
    const void* xprev, const int* flagp, const bf16* wcb, float* xdense){
  __shared__ __align__(16) unsigned short bt[64 * 66];
  if (*flagp) cross_body(xdirb, (const float*)xprev, wcb, xdense, bt);
  else        cross_body(xdirb, (const bf16*)xprev, wcb, xdense, bt);
}

// ---------------------------------------------------------------------------
// K5: 1x1 conv 64->256 + bias + sigmoid, xab = bf16(xdense * attn). grid (64,64).
// ---------------------------------------------------------------------------
__global__ __launch_bounds__(256) void k_attn(
    const float* __restrict__ abuf, const float* __restrict__ cw,
    const float* __restrict__ cb, const float* __restrict__ xdense,
    unsigned short* __restrict__ xab){
  const int q0 = blockIdx.x * 256;
  const int b = q0 >> 12, p0 = q0 & 4095;
  const int co0 = blockIdx.y * 4;
  const int p = p0 + threadIdx.x;
  float acc[4] = {0,0,0,0};
  const float* ab = abuf + b * 64 * 4096;
  for (int c = 0; c < 64; c++){
    float av = ab[c * 4096 + p];
    acc[0] += cw[(co0 + 0) * 64 + c] * av;
    acc[1] += cw[(co0 + 1) * 64 + c] * av;
    acc[2] += cw[(co0 + 2) * 64 + c] * av;
    acc[3] += cw[(co0 + 3) * 64 + c] * av;
  }
  #pragma unroll
  for (int j = 0; j < 4; j++){
    int co = co0 + j;
    float attn = sigf(acc[j] + cb[co]);
    int idx = (b * 256 + co) * 4096 + p;
    xab[idx] = f2h(xdense[idx] * attn);
  }
}

// ---------------------------------------------------------------------------
// K6: 1x1 conv 256->256 — MFMA GEMM + bias + BN + SiLU + residual (dual).
// Same skeleton as cross, K=256, B from xab (bf16).
// ---------------------------------------------------------------------------
template<typename T>
__device__ __forceinline__ void out_body(const unsigned short* __restrict__ xab,
    const bf16* __restrict__ wob, const float* __restrict__ cb,
    const float* __restrict__ gam, const float* __restrict__ bet,
    const float* __restrict__ mea, const float* __restrict__ var,
    const T* __restrict__ xres, T* __restrict__ out, unsigned short* bt){
  const int bx = blockIdx.x;
  const int b = bx >> 6, p0 = (bx & 63) * 64;
  const int co0 = blockIdx.y * 64;
  const int t = threadIdx.x;
  const int w = t >> 6, l = t & 63, lm = l & 15, lq = l >> 4;
  f32x4 acc[4];
  #pragma unroll
  for (int m = 0; m < 4; m++) acc[m] = (f32x4){0.f,0.f,0.f,0.f};
  for (int cc = 0; cc < 256; cc += 64){
    __syncthreads();
    #pragma unroll
    for (int j = 0; j < 16; j++){
      const int k = w * 16 + j;
      bt[l * 66 + k] = xab[(b*256 + cc + k)*4096 + p0 + l];
    }
    __syncthreads();
    #pragma unroll
    for (int ks = 0; ks < 2; ks++){
      short8 bfr = ld8u(bt + (w*16 + lm)*66 + ks*32 + lq*8);
      #pragma unroll
      for (int m = 0; m < 4; m++){
        short8 afr = *(const short8*)(wob + (co0 + m*16 + lm)*256 + cc + ks*32 + lq*8);
        acc[m] = __builtin_amdgcn_mfma_f32_16x16x32_bf16(afr, bfr, acc[m], 0, 0, 0);
      }
    }
  }
  const int px = p0 + w*16 + lm;
  #pragma unroll
  for (int m = 0; m < 4; m++){
    #pragma unroll
    for (int r = 0; r < 4; r++){
      const int co = co0 + m*16 + lq*4 + r;
      float v = acc[m][r] + cb[co];
      float inv = gam[co] * rsqrtf(var[co] + 1e-5f);
      v = v * inv + (bet[co] - mea[co] * inv);
      v = v * sigf(v);
      const int idx = (b*256 + co)*4096 + px;
      stv(out, idx, v + ldv(xres, idx));
    }
  }
}

__global__ __launch_bounds__(256) void k_out_m(const unsigned short* xab,
    const bf16* wob, const float* cb, const float* gam, const float* bet,
    const float* mea, const float* var, const void* xres, void* out,
    const int* flagp){
  __shared__ __align__(16) unsigned short bt[64 * 66];
  if (*flagp) out_body(xab, wob, cb, gam, bet, mea, var, (const float*)xres, (float*)out, bt);
  else        out_body(xab, wob, cb, gam, bet, mea, var, (const bf16*)xres, (bf16*)out, bt);
}

// ---------------------------------------------------------------------------
extern "C" void kernel_launch(void* const* d_in, const int* in_sizes, int n_in,
                              void* d_out, int out_size, void* d_ws, size_t ws_size,
                              hipStream_t stream) {
  const void* x      = d_in[0];
  const void* x_prev = d_in[1];

  float* ws   = (float*)d_ws;
  int*   flag = (int*)ws;                 // ws[0..15] reserved
  float* cpar = ws + 16;                  // canonical fp32 params (551264 f)
  float* cb_off   = cpar + 41472;
  float* cb_g1    = cpar + 467488;
  float* cg1_gam  = cpar + 467552;
  float* cg1_bet  = cpar + 467616;
  float* cg1_mea  = cpar + 467680;
  float* cg1_var  = cpar + 467744;
  float* cw_g2    = cpar + 467808;
  float* cb_g2    = cpar + 484192;
  float* cb_out   = cpar + 549984;
  float* co_gam   = cpar + 550240;
  float* co_bet   = cpar + 550496;
  float* co_mea   = cpar + 550752;
  float* co_var   = cpar + 551008;

  float* q = ws + 16 + 551264;
  bf16*  wdefb   = (bf16*)q;  q += 73728;   // 147456 bf16
  bf16*  woffb   = (bf16*)q;  q += 36864;   // 73728 bf16 (18->32 pad)
  bf16*  wg1b    = (bf16*)q;  q += 73728;   // 147456 bf16
  bf16*  wcrossb = (bf16*)q;  q += 65536;   // 131072 bf16
  bf16*  woutb   = (bf16*)q;  q += 32768;   // 65536 bf16
  float* offc    = q;         q += 294912;  // 4*18*4096 f32
  unsigned short* xdirb = (unsigned short*)q; q += 2097152; // 4*256*4096 bf16
  float* xdense  = q;         q += 4194304; // 4*256*4096 f32
  float* abuf    = q;         q += 1048576; // 4*64*4096 f32
  unsigned short* xab = xdirb;              // reuse (xdirb dead after cross)

  ParamSrc ps;
  for (int i = 0; i < 18; i++) ps.p[i] = d_in[2 + i];

  k_detect<<<dim3(1), 256, 0, stream>>>((const unsigned short*)x, flag);
  k_convert<<<dim3(96, 23), 256, 0, stream>>>(ps, flag, cpar, wdefb, woffb,
                                              wg1b, wcrossb, woutb);
  k_coff_m<<<dim3(256), 256, 0, stream>>>(x, flag, woffb, cb_off, offc);
  k_deform<<<dim3(512, 4), 256, 0, stream>>>(x, flag, offc, wdefb, xdirb);
  k_cross_m<<<dim3(256, 4), 256, 0, stream>>>(xdirb, x_prev, flag, wcrossb, xdense);
  k_g1_m<<<dim3(256), 256, 0, stream>>>(xdense, wg1b, cb_g1, cg1_gam, cg1_bet,
                                        cg1_mea, cg1_var, abuf);
  k_attn<<<dim3(64, 64), 256, 0, stream>>>(abuf, cw_g2, cb_g2, xdense, xab);
  k_out_m<<<dim3(256, 4), 256, 0, stream>>>(xab, woutb, cb_out, co_gam, co_bet,
                                            co_mea, co_var, x, d_out, flag);
}

// Round 6
// 541.608 us; speedup vs baseline: 1.1448x; 1.1448x over previous
//
#include <hip/hip_runtime.h>
#include <hip/hip_bf16.h>

using bf16 = __hip_bfloat16;
typedef __attribute__((ext_vector_type(8))) short short8;
typedef __attribute__((ext_vector_type(4))) float f32x4;

__device__ __forceinline__ float b2f(bf16 v){ return __bfloat162float(v); }
__device__ __forceinline__ float sigf(float v){ return 1.f/(1.f + __expf(-v)); }
__device__ __forceinline__ float ldv(const float* p, int i){ return p[i]; }
__device__ __forceinline__ float ldv(const bf16* p, int i){ return b2f(p[i]); }
__device__ __forceinline__ void stv(float* p, int i, float v){ p[i] = v; }
__device__ __forceinline__ void stv(bf16* p, int i, float v){ p[i] = __float2bfloat16(v); }
__device__ __forceinline__ unsigned short f2h(float v){
  bf16 h = __float2bfloat16(v); return *(unsigned short*)&h;
}
// 8 bf16 from 4-B-aligned LDS via 4x b32 (conflict-free with odd-word strides)
__device__ __forceinline__ short8 ld8u(const unsigned short* p){
  union { unsigned int u[4]; short8 s; } v;
  const unsigned int* q = (const unsigned int*)p;
  v.u[0] = q[0]; v.u[1] = q[1]; v.u[2] = q[2]; v.u[3] = q[3];
  return v.s;
}

// ---------------------------------------------------------------------------
// K0: dtype detect. flag=1 => inputs are f32.
// ---------------------------------------------------------------------------
__global__ __launch_bounds__(256) void k_detect(const unsigned short* xs, int* flag){
  __shared__ int cnt;
  if (threadIdx.x == 0) cnt = 0;
  __syncthreads();
  int local = 0;
  for (int i = threadIdx.x; i < 16384; i += 256){
    if (((xs[i] >> 7) & 0xFF) == 0xFF) local++;
  }
  if (local) atomicAdd(&cnt, local);
  __syncthreads();
  if (threadIdx.x == 0) *flag = (cnt > 0) ? 1 : 0;
}

// ---------------------------------------------------------------------------
// K0b: canonicalize params. 0-17: fp32 in cpar; 18: w_def->bf16;
// 19: w_off->bf16 pad 18->32 rows; 20: w_g1->bf16; 21: w_cross->bf16;
// 22: w_out->bf16. grid (96, 23).
// ---------------------------------------------------------------------------
struct ParamSrc { const void* p[18]; };

__global__ __launch_bounds__(256) void k_convert(ParamSrc ps, const int* flagp,
    float* cpar, bf16* wdefb, bf16* woffb, bf16* wg1b, bf16* wcrossb, bf16* woutb){
  static constexpr int n[23]   = {41472,18,147456,131072,147456,64,64,64,64,64,
                                  16384,256,65536,256,256,256,256,256,
                                  147456,73728,147456,131072,65536};
  static constexpr int off[18] = {0,41472,41504,188960,320032,467488,467552,467616,
                                  467680,467744,467808,484192,484448,549984,550240,
                                  550496,550752,551008};
  const int s = blockIdx.y;
  const bool f32 = (*flagp != 0);
  if (s >= 18){
    static constexpr int srcs[5] = {2, 0, 4, 3, 12};
    const int src_slot = srcs[s - 18];
    bf16* dsts[5] = {wdefb, woffb, wg1b, wcrossb, woutb};
    bf16* dst = dsts[s - 18];
    const int nsrc = (s == 19) ? 41472 : n[s];
    if (f32){
      const float* src = (const float*)ps.p[src_slot];
      for (int i = blockIdx.x * 256 + threadIdx.x; i < n[s]; i += gridDim.x * 256)
        dst[i] = (i < nsrc) ? __float2bfloat16(src[i]) : __float2bfloat16(0.f);
    } else {
      const bf16* src = (const bf16*)ps.p[src_slot];
      for (int i = blockIdx.x * 256 + threadIdx.x; i < n[s]; i += gridDim.x * 256)
        dst[i] = (i < nsrc) ? src[i] : __float2bfloat16(0.f);
    }
    return;
  }
  float* dst = cpar + off[s];
  if (f32){
    const float* src = (const float*)ps.p[s];
    for (int i = blockIdx.x * 256 + threadIdx.x; i < n[s]; i += gridDim.x * 256)
      dst[i] = src[i];
  } else {
    const bf16* src = (const bf16*)ps.p[s];
    for (int i = blockIdx.x * 256 + threadIdx.x; i < n[s]; i += gridDim.x * 256)
      dst[i] = b2f(src[i]);
  }
}

// ---------------------------------------------------------------------------
// 3x3 pad=1 conv, v2: block = 16-px quarter-row, 256 thr, grid 1024
// (b*256 + y*4 + quarter). cols [16 px][290 k] u16 (145-word odd stride =>
// conflict-free). Gather: lane->px coalesced loads, packed b32 LDS writes.
// MFMA 16x16x32: wave = m-tile (g1: 4 tiles of co); KSPLIT (coff): wave&1 =
// m-tile, wave>>1 = K-half, LDS reduction at end.
// ---------------------------------------------------------------------------
#define C3ROW 290

template<typename T, bool KSPLIT, bool EPI>
__device__ __forceinline__ void conv3v2_body(const T* __restrict__ xin,
    const bf16* __restrict__ wb, const float* __restrict__ cbv,
    const float* __restrict__ gam, const float* __restrict__ bet,
    const float* __restrict__ mea, const float* __restrict__ var,
    float* __restrict__ outp, int CO, unsigned short* cols){
  const int bx = blockIdx.x;
  const int b = bx >> 8, y = (bx >> 2) & 63, qp = bx & 3;
  const int px0 = qp * 16;
  const int t = threadIdx.x;
  const int px = t & 15, ks = t >> 4;          // gather roles
  const int w = t >> 6, l = t & 63;            // mfma roles
  const int lm = l & 15, lq = l >> 4;
  const int mw = KSPLIT ? (w & 1) : w;
  f32x4 acc = {0.f, 0.f, 0.f, 0.f};
  const int xcol = px0 + px;

  for (int ci = 0; ci < 8; ci++){
    __syncthreads();
    // ---- gather: slot ks covers 2 channels x 9 taps = 18 k values
    {
      float v[18];
      #pragma unroll
      for (int c2 = 0; c2 < 2; c2++){
        const int chl = ks * 2 + c2;
        const T* xc = xin + (b * 256 + ci * 32 + chl) * 4096;
        #pragma unroll
        for (int ti = 0; ti < 3; ti++){
          const int yy = y + ti - 1;
          const bool vy = (unsigned)yy < 64u;
          #pragma unroll
          for (int tj = 0; tj < 3; tj++){
            const int xc2 = xcol + tj - 1;
            v[c2 * 9 + ti * 3 + tj] =
              (vy && (unsigned)xc2 < 64u) ? ldv(xc, yy * 64 + xc2) : 0.f;
          }
        }
      }
      unsigned int* c32 = (unsigned int*)(cols + px * C3ROW + ks * 18);
      #pragma unroll
      for (int i = 0; i < 9; i++)
        c32[i] = (unsigned int)f2h(v[2*i]) | ((unsigned int)f2h(v[2*i+1]) << 16);
    }
    __syncthreads();
    // ---- MFMA: 9 ksteps of 32 over this chunk
    if (!KSPLIT || ((ci >> 2) == (w >> 1))){
      const bf16* arow = wb + (mw * 16 + lm) * 2304 + ci * 288 + lq * 8;
      const unsigned short* brow = cols + lm * C3ROW + lq * 8;
      #pragma unroll
      for (int kk = 0; kk < 288; kk += 32){
        short8 bfr = ld8u(brow + kk);
        short8 afr = *(const short8*)(arow + kk);
        acc = __builtin_amdgcn_mfma_f32_16x16x32_bf16(afr, bfr, acc, 0, 0, 0);
      }
    }
  }
  if constexpr (KSPLIT){
    __syncthreads();
    float* red = (float*)cols;
    if (w >= 2){
      #pragma unroll
      for (int r = 0; r < 4; r++) red[(w - 2) * 256 + l * 4 + r] = acc[r];
    }
    __syncthreads();
    if (w >= 2) return;
    #pragma unroll
    for (int r = 0; r < 4; r++) acc[r] += red[w * 256 + l * 4 + r];
  }
  // ---- epilogue: D col=lane&15 (px), row=(lane>>4)*4+reg (co)
  const int pxg = y * 64 + px0 + lm;
  #pragma unroll
  for (int r = 0; r < 4; r++){
    const int co = mw * 16 + lq * 4 + r;
    if (co >= CO) continue;
    float v = acc[r] + cbv[co];
    if constexpr (EPI){
      float inv = gam[co] * rsqrtf(var[co] + 1e-5f);
      v = v * inv + (bet[co] - mea[co] * inv);
      v = v * sigf(v);
    }
    outp[(b * CO + co) * 4096 + pxg] = v;
  }
}

__global__ __launch_bounds__(256) void k_coff2(const void* x, const int* flagp,
    const bf16* woffb, const float* cb, float* offc){
  __shared__ __align__(16) unsigned short cols[16 * C3ROW];
  if (*flagp) conv3v2_body<float, true, false>((const float*)x, woffb, cb,
                  nullptr, nullptr, nullptr, nullptr, offc, 18, cols);
  else        conv3v2_body<bf16, true, false>((const bf16*)x, woffb, cb,
                  nullptr, nullptr, nullptr, nullptr, offc, 18, cols);
}

__global__ __launch_bounds__(256) void k_g12(const float* xdense,
    const bf16* wg1b, const float* cb, const float* gam, const float* bet,
    const float* mea, const float* var, float* abuf){
  __shared__ __align__(16) unsigned short cols[16 * C3ROW];
  conv3v2_body<float, false, true>(xdense, wg1b, cb, gam, bet, mea, var,
                                   abuf, 64, cols);
}

// ---------------------------------------------------------------------------
// K2: deformable conv, MFMA, K-chunked LDS, conflict-free strides.
// Block = (group g, 32 px), grid (512, 4), 256 thr. Output bf16.
// NOTE: no min-waves launch bound — R5's (256,4) capped VGPR at 64 and
// spilled ~180 MB to scratch (WRITE_SIZE 16->184 MB).
// ---------------------------------------------------------------------------
#define CROW2 290

template<typename T>
__device__ __forceinline__ void deform_body(const T* __restrict__ x,
    const float* __restrict__ offc, const bf16* __restrict__ wdefb,
    unsigned short* __restrict__ xdirb, unsigned short* cols){
  const int g = blockIdx.y;
  const int q0 = blockIdx.x * 32;
  const int b = q0 >> 12, p0 = q0 & 4095;
  const int t = threadIdx.x;
  const int pos = t & 31, cslot = t >> 5;
  const int p = p0 + pos;
  const int y = p >> 6, xx = p & 63;
  const int w = t >> 6, l = t & 63, lrow = l & 15, lhi = l >> 4;
  float dyv[9], dxv[9];
  {
    const float* ob = offc + b * 18 * 4096 + p;
    #pragma unroll
    for (int k = 0; k < 9; k++){ dyv[k] = ob[(2*k)*4096]; dxv[k] = ob[(2*k+1)*4096]; }
  }
  f32x4 acc0 = {0.f,0.f,0.f,0.f}, acc1 = {0.f,0.f,0.f,0.f};
  #pragma unroll 1
  for (int cc = 0; cc < 2; cc++){
    __syncthreads();
    const T* xg = x + (((b*4 + g)*64) + cc*32) * 4096;
    #pragma unroll
    for (int k = 0; k < 9; k++){
      float py  = (float)(y + k/3 - 1) + dyv[k];
      float pxf = (float)(xx + k%3 - 1) + dxv[k];
      float y0f = floorf(py), x0f = floorf(pxf);
      int y0 = (int)y0f, x0 = (int)x0f;
      float wy1 = py - y0f, wx1 = pxf - x0f;
      float wy0 = 1.f - wy1, wx0 = 1.f - wx1;
      bool vy0 = (unsigned)y0 < 64u, vy1 = (unsigned)(y0+1) < 64u;
      bool vx0 = (unsigned)x0 < 64u, vx1 = (unsigned)(x0+1) < 64u;
      float w00 = (vy0 && vx0) ? wy0*wx0 : 0.f;
      float w01 = (vy0 && vx1) ? wy0*wx1 : 0.f;
      float w10 = (vy1 && vx0) ? wy1*wx0 : 0.f;
      float w11 = (vy1 && vx1) ? wy1*wx1 : 0.f;
      int yc0 = min(max(y0,0),63),   yc1 = min(max(y0+1,0),63);
      int xc0 = min(max(x0,0),63),   xc1 = min(max(x0+1,0),63);
      int i00 = yc0*64+xc0, i01 = yc0*64+xc1, i10 = yc1*64+xc0, i11 = yc1*64+xc1;
      #pragma unroll
      for (int j = 0; j < 4; j++){
        const int cl = cslot*4 + j;
        const T* xc = xg + cl*4096;
        float val = w00*ldv(xc,i00) + w01*ldv(xc,i01)
                  + w10*ldv(xc,i10) + w11*ldv(xc,i11);
        cols[pos*CROW2 + cl*9 + k] = f2h(val);
      }
    }
    __syncthreads();
    const bf16* wr = wdefb + (g*64 + w*16 + lrow)*576 + cc*288;
    const unsigned short* b0p = cols + lrow*CROW2;
    const unsigned short* b1p = cols + (16+lrow)*CROW2;
    #pragma unroll
    for (int kk = 0; kk < 288; kk += 32){
      const int ko = kk + lhi*8;
      short8 a  = *(const short8*)(wr + ko);
      short8 b0 = ld8u(b0p + ko);
      short8 b1 = ld8u(b1p + ko);
      acc0 = __builtin_amdgcn_mfma_f32_16x16x32_bf16(a, b0, acc0, 0, 0, 0);
      acc1 = __builtin_amdgcn_mfma_f32_16x16x32_bf16(a, b1, acc1, 0, 0, 0);
    }
  }
  const int co_base = g*64 + w*16 + lhi*4;
  #pragma unroll
  for (int r = 0; r < 4; r++){
    unsigned short* xo = xdirb + (b*256 + co_base + r)*4096 + p0 + lrow;
    xo[0]  = f2h(acc0[r]);
    xo[16] = f2h(acc1[r]);
  }
}

__global__ __launch_bounds__(256) void k_deform(const void* x, const int* flagp,
    const float* offc, const bf16* wdefb, unsigned short* xdirb){
  __shared__ __align__(16) unsigned short cols[32 * CROW2];
  if (*flagp) deform_body((const float*)x, offc, wdefb, xdirb, cols);
  else        deform_body((const bf16*)x, offc, wdefb, xdirb, cols);
}

// ---------------------------------------------------------------------------
// K3: 1x1 conv concat([x_dir, x_prev]) * w_cross — MFMA GEMM.
// Block = 64 px x 64 co, grid (256, 4), 256 thr.
// ---------------------------------------------------------------------------
template<typename T>
__device__ __forceinline__ void cross_body(const unsigned short* __restrict__ xdirb,
    const T* __restrict__ xprev, const bf16* __restrict__ wcb,
    float* __restrict__ xdense, unsigned short* bt){
  const int bx = blockIdx.x;
  const int b = bx >> 6, p0 = (bx & 63) * 64;
  const int co0 = blockIdx.y * 64;
  const int t = threadIdx.x;
  const int w = t >> 6, l = t & 63, lm = l & 15, lq = l >> 4;
  f32x4 acc[4];
  #pragma unroll
  for (int m = 0; m < 4; m++) acc[m] = (f32x4){0.f,0.f,0.f,0.f};
  for (int cc = 0; cc < 512; cc += 64){
    __syncthreads();
    #pragma unroll
    for (int j = 0; j < 16; j++){
      const int k = w * 16 + j;
      const int ci = cc + k;
      unsigned short hv;
      if (ci < 256) hv = xdirb[(b*256 + ci)*4096 + p0 + l];
      else          hv = f2h(ldv(xprev, (b*256 + ci - 256)*4096 + p0 + l));
      bt[l * 66 + k] = hv;
    }
    __syncthreads();
    #pragma unroll
    for (int ks = 0; ks < 2; ks++){
      short8 bfr = ld8u(bt + (w*16 + lm)*66 + ks*32 + lq*8);
      #pragma unroll
      for (int m = 0; m < 4; m++){
        short8 afr = *(const short8*)(wcb + (co0 + m*16 + lm)*512 + cc + ks*32 + lq*8);
        acc[m] = __builtin_amdgcn_mfma_f32_16x16x32_bf16(afr, bfr, acc[m], 0, 0, 0);
      }
    }
  }
  const int px = p0 + w*16 + lm;
  #pragma unroll
  for (int m = 0; m < 4; m++){
    #pragma unroll
    for (int r = 0; r < 4; r++)
      xdense[(b*256 + co0 + m*16 + lq*4 + r)*4096 + px] = acc[m][r];
  }
}

__global__ __launch_bounds__(256) void k_cross_m(const unsigned short* xdirb,
    const void* xprev, const int* flagp, const bf16* wcb, float* xdense){
  __shared__ __align__(16) unsigned short bt[64 * 66];
  if (*flagp) cross_body(xdirb, (const float*)xprev, wcb, xdense, bt);
  else        cross_body(xdirb, (const bf16*)xprev, wcb, xdense, bt);
}

// ---------------------------------------------------------------------------
// K5: 1x1 conv 64->256 + bias + sigmoid, xab = bf16(xdense * attn). grid (64,64).
// ---------------------------------------------------------------------------
__global__ __launch_bounds__(256) void k_attn(
    const float* __restrict__ abuf, const float* __restrict__ cw,
    const float* __restrict__ cb, const float* __restrict__ xdense,
    unsigned short* __restrict__ xab){
  const int q0 = blockIdx.x * 256;
  const int b = q0 >> 12, p0 = q0 & 4095;
  const int co0 = blockIdx.y * 4;
  const int p = p0 + threadIdx.x;
  float acc[4] = {0,0,0,0};
  const float* ab = abuf + b * 64 * 4096;
  for (int c = 0; c < 64; c++){
    float av = ab[c * 4096 + p];
    acc[0] += cw[(co0 + 0) * 64 + c] * av;
    acc[1] += cw[(co0 + 1) * 64 + c] * av;
    acc[2] += cw[(co0 + 2) * 64 + c] * av;
    acc[3] += cw[(co0 + 3) * 64 + c] * av;
  }
  #pragma unroll
  for (int j = 0; j < 4; j++){
    int co = co0 + j;
    float attn = sigf(acc[j] + cb[co]);
    int idx = (b * 256 + co) * 4096 + p;
    xab[idx] = f2h(xdense[idx] * attn);
  }
}

// ---------------------------------------------------------------------------
// K6: 1x1 conv 256->256 — MFMA GEMM + bias + BN + SiLU + residual (dual).
// ---------------------------------------------------------------------------
template<typename T>
__device__ __forceinline__ void out_body(const unsigned short* __restrict__ xab,
    const bf16* __restrict__ wob, const float* __restrict__ cb,
    const float* __restrict__ gam, const float* __restrict__ bet,
    const float* __restrict__ mea, const float* __restrict__ var,
    const T* __restrict__ xres, T* __restrict__ out, unsigned short* bt){
  const int bx = blockIdx.x;
  const int b = bx >> 6, p0 = (bx & 63) * 64;
  const int co0 = blockIdx.y * 64;
  const int t = threadIdx.x;
  const int w = t >> 6, l = t & 63, lm = l & 15, lq = l >> 4;
  f32x4 acc[4];
  #pragma unroll
  for (int m = 0; m < 4; m++) acc[m] = (f32x4){0.f,0.f,0.f,0.f};
  for (int cc = 0; cc < 256; cc += 64){
    __syncthreads();
    #pragma unroll
    for (int j = 0; j < 16; j++){
      const int k = w * 16 + j;
      bt[l * 66 + k] = xab[(b*256 + cc + k)*4096 + p0 + l];
    }
    __syncthreads();
    #pragma unroll
    for (int ks = 0; ks < 2; ks++){
      short8 bfr = ld8u(bt + (w*16 + lm)*66 + ks*32 + lq*8);
      #pragma unroll
      for (int m = 0; m < 4; m++){
        short8 afr = *(const short8*)(wob + (co0 + m*16 + lm)*256 + cc + ks*32 + lq*8);
        acc[m] = __builtin_amdgcn_mfma_f32_16x16x32_bf16(afr, bfr, acc[m], 0, 0, 0);
      }
    }
  }
  const int px = p0 + w*16 + lm;
  #pragma unroll
  for (int m = 0; m < 4; m++){
    #pragma unroll
    for (int r = 0; r < 4; r++){
      const int co = co0 + m*16 + lq*4 + r;
      float v = acc[m][r] + cb[co];
      float inv = gam[co] * rsqrtf(var[co] + 1e-5f);
      v = v * inv + (bet[co] - mea[co] * inv);
      v = v * sigf(v);
      const int idx = (b*256 + co)*4096 + px;
      stv(out, idx, v + ldv(xres, idx));
    }
  }
}

__global__ __launch_bounds__(256) void k_out_m(const unsigned short* xab,
    const bf16* wob, const float* cb, const float* gam, const float* bet,
    const float* mea, const float* var, const void* xres, void* out,
    const int* flagp){
  __shared__ __align__(16) unsigned short bt[64 * 66];
  if (*flagp) out_body(xab, wob, cb, gam, bet, mea, var, (const float*)xres, (float*)out, bt);
  else        out_body(xab, wob, cb, gam, bet, mea, var, (const bf16*)xres, (bf16*)out, bt);
}

// ---------------------------------------------------------------------------
extern "C" void kernel_launch(void* const* d_in, const int* in_sizes, int n_in,
                              void* d_out, int out_size, void* d_ws, size_t ws_size,
                              hipStream_t stream) {
  const void* x      = d_in[0];
  const void* x_prev = d_in[1];

  float* ws   = (float*)d_ws;
  int*   flag = (int*)ws;                 // ws[0..15] reserved
  float* cpar = ws + 16;                  // canonical fp32 params (551264 f)
  float* cb_off   = cpar + 41472;
  float* cb_g1    = cpar + 467488;
  float* cg1_gam  = cpar + 467552;
  float* cg1_bet  = cpar + 467616;
  float* cg1_mea  = cpar + 467680;
  float* cg1_var  = cpar + 467744;
  float* cw_g2    = cpar + 467808;
  float* cb_g2    = cpar + 484192;
  float* cb_out   = cpar + 549984;
  float* co_gam   = cpar + 550240;
  float* co_bet   = cpar + 550496;
  float* co_mea   = cpar + 550752;
  float* co_var   = cpar + 551008;

  float* q = ws + 16 + 551264;
  bf16*  wdefb   = (bf16*)q;  q += 73728;   // 147456 bf16
  bf16*  woffb   = (bf16*)q;  q += 36864;   // 73728 bf16 (18->32 pad)
  bf16*  wg1b    = (bf16*)q;  q += 73728;   // 147456 bf16
  bf16*  wcrossb = (bf16*)q;  q += 65536;   // 131072 bf16
  bf16*  woutb   = (bf16*)q;  q += 32768;   // 65536 bf16
  float* offc    = q;         q += 294912;  // 4*18*4096 f32
  unsigned short* xdirb = (unsigned short*)q; q += 2097152; // 4*256*4096 bf16
  float* xdense  = q;         q += 4194304; // 4*256*4096 f32
  float* abuf    = q;         q += 1048576; // 4*64*4096 f32
  unsigned short* xab = xdirb;              // reuse (xdirb dead after cross)

  ParamSrc ps;
  for (int i = 0; i < 18; i++) ps.p[i] = d_in[2 + i];

  k_detect<<<dim3(1), 256, 0, stream>>>((const unsigned short*)x, flag);
  k_convert<<<dim3(96, 23), 256, 0, stream>>>(ps, flag, cpar, wdefb, woffb,
                                              wg1b, wcrossb, woutb);
  k_coff2<<<dim3(1024), 256, 0, stream>>>(x, flag, woffb, cb_off, offc);
  k_deform<<<dim3(512, 4), 256, 0, stream>>>(x, flag, offc, wdefb, xdirb);
  k_cross_m<<<dim3(256, 4), 256, 0, stream>>>(xdirb, x_prev, flag, wcrossb, xdense);
  k_g12<<<dim3(1024), 256, 0, stream>>>(xdense, wg1b, cb_g1, cg1_gam, cg1_bet,
                                        cg1_mea, cg1_var, abuf);
  k_attn<<<dim3(64, 64), 256, 0, stream>>>(abuf, cw_g2, cb_g2, xdense, xab);
  k_out_m<<<dim3(256, 4), 256, 0, stream>>>(xab, woutb, cb_out, co_gam, co_bet,
                                            co_mea, co_var, x, d_out, flag);
}

// Round 7
// 532.673 us; speedup vs baseline: 1.1640x; 1.0168x over previous
//
#include <hip/hip_runtime.h>
#include <hip/hip_bf16.h>

using bf16 = __hip_bfloat16;
typedef __attribute__((ext_vector_type(8))) short short8;
typedef __attribute__((ext_vector_type(4))) float f32x4;

__device__ __forceinline__ float b2f(bf16 v){ return __bfloat162float(v); }
__device__ __forceinline__ float sigf(float v){ return 1.f/(1.f + __expf(-v)); }
__device__ __forceinline__ float ldv(const float* p, int i){ return p[i]; }
__device__ __forceinline__ float ldv(const bf16* p, int i){ return b2f(p[i]); }
__device__ __forceinline__ void stv(float* p, int i, float v){ p[i] = v; }
__device__ __forceinline__ void stv(bf16* p, int i, float v){ p[i] = __float2bfloat16(v); }
__device__ __forceinline__ unsigned short f2h(float v){
  bf16 h = __float2bfloat16(v); return *(unsigned short*)&h;
}
__device__ __forceinline__ unsigned short ldh(const float* p, int i){ return f2h(p[i]); }
__device__ __forceinline__ unsigned short ldh(const bf16* p, int i){
  return *(const unsigned short*)(p + i);
}
// 8 bf16 from LDS: 4x ds_read_b32 at word stride S (k-pair layout)
__device__ __forceinline__ short8 ld8s(const unsigned int* p, int S){
  union { unsigned int u[4]; short8 s; } v;
  v.u[0] = p[0]; v.u[1] = p[S]; v.u[2] = p[2*S]; v.u[3] = p[3*S];
  return v.s;
}

// ---------------------------------------------------------------------------
// K0: dtype detect. flag=1 => inputs are f32.
// ---------------------------------------------------------------------------
__global__ __launch_bounds__(256) void k_detect(const unsigned short* xs, int* flag){
  __shared__ int cnt;
  if (threadIdx.x == 0) cnt = 0;
  __syncthreads();
  int local = 0;
  for (int i = threadIdx.x; i < 16384; i += 256){
    if (((xs[i] >> 7) & 0xFF) == 0xFF) local++;
  }
  if (local) atomicAdd(&cnt, local);
  __syncthreads();
  if (threadIdx.x == 0) *flag = (cnt > 0) ? 1 : 0;
}

// ---------------------------------------------------------------------------
// K0b: canonicalize params. 0-17: fp32 in cpar; 18: w_def->bf16;
// 19: w_off->bf16 pad 18->32 rows; 20: w_g1->bf16; 21: w_cross->bf16;
// 22: w_out->bf16. grid (96, 23).
// ---------------------------------------------------------------------------
struct ParamSrc { const void* p[18]; };

__global__ __launch_bounds__(256) void k_convert(ParamSrc ps, const int* flagp,
    float* cpar, bf16* wdefb, bf16* woffb, bf16* wg1b, bf16* wcrossb, bf16* woutb){
  static constexpr int n[23]   = {41472,18,147456,131072,147456,64,64,64,64,64,
                                  16384,256,65536,256,256,256,256,256,
                                  147456,73728,147456,131072,65536};
  static constexpr int off[18] = {0,41472,41504,188960,320032,467488,467552,467616,
                                  467680,467744,467808,484192,484448,549984,550240,
                                  550496,550752,551008};
  const int s = blockIdx.y;
  const bool f32 = (*flagp != 0);
  if (s >= 18){
    static constexpr int srcs[5] = {2, 0, 4, 3, 12};
    const int src_slot = srcs[s - 18];
    bf16* dsts[5] = {wdefb, woffb, wg1b, wcrossb, woutb};
    bf16* dst = dsts[s - 18];
    const int nsrc = (s == 19) ? 41472 : n[s];
    if (f32){
      const float* src = (const float*)ps.p[src_slot];
      for (int i = blockIdx.x * 256 + threadIdx.x; i < n[s]; i += gridDim.x * 256)
        dst[i] = (i < nsrc) ? __float2bfloat16(src[i]) : __float2bfloat16(0.f);
    } else {
      const bf16* src = (const bf16*)ps.p[src_slot];
      for (int i = blockIdx.x * 256 + threadIdx.x; i < n[s]; i += gridDim.x * 256)
        dst[i] = (i < nsrc) ? src[i] : __float2bfloat16(0.f);
    }
    return;
  }
  float* dst = cpar + off[s];
  if (f32){
    const float* src = (const float*)ps.p[s];
    for (int i = blockIdx.x * 256 + threadIdx.x; i < n[s]; i += gridDim.x * 256)
      dst[i] = src[i];
  } else {
    const bf16* src = (const bf16*)ps.p[s];
    for (int i = blockIdx.x * 256 + threadIdx.x; i < n[s]; i += gridDim.x * 256)
      dst[i] = b2f(src[i]);
  }
}

// ---------------------------------------------------------------------------
// 3x3 pad=1 conv v3: block = 16-px quarter-row, grid 1024. LDS cols in
// k-pair u32 layout [k2][18-word stride]: B-frag reads bank = px + 8*lhi
// (uniform 2-way = free). KSPLIT: wave&1 = m-tile, wave>>1 = K-half.
// ---------------------------------------------------------------------------
template<typename T, bool KSPLIT, bool EPI>
__device__ __forceinline__ void conv3v3_body(const T* __restrict__ xin,
    const bf16* __restrict__ wb, const float* __restrict__ cbv,
    const float* __restrict__ gam, const float* __restrict__ bet,
    const float* __restrict__ mea, const float* __restrict__ var,
    float* __restrict__ outp, int CO, unsigned int* cols32){
  const int bx = blockIdx.x;
  const int b = bx >> 8, y = (bx >> 2) & 63, qp = bx & 3;
  const int px0 = qp * 16;
  const int t = threadIdx.x;
  const int px = t & 15, ks = t >> 4;          // gather roles
  const int w = t >> 6, l = t & 63;            // mfma roles
  const int lm = l & 15, lq = l >> 4;
  const int mw = KSPLIT ? (w & 1) : w;
  f32x4 acc = {0.f, 0.f, 0.f, 0.f};
  const int xcol = px0 + px;

  for (int ci = 0; ci < 8; ci++){
    __syncthreads();
    // ---- gather: slot ks covers 2 channels x 9 taps = 18 k (9 k-pairs)
    {
      float v[18];
      #pragma unroll
      for (int c2 = 0; c2 < 2; c2++){
        const int chl = ks * 2 + c2;
        const T* xc = xin + (b * 256 + ci * 32 + chl) * 4096;
        #pragma unroll
        for (int ti = 0; ti < 3; ti++){
          const int yy = y + ti - 1;
          const bool vy = (unsigned)yy < 64u;
          #pragma unroll
          for (int tj = 0; tj < 3; tj++){
            const int xc2 = xcol + tj - 1;
            v[c2 * 9 + ti * 3 + tj] =
              (vy && (unsigned)xc2 < 64u) ? ldv(xc, yy * 64 + xc2) : 0.f;
          }
        }
      }
      #pragma unroll
      for (int i = 0; i < 9; i++)
        cols32[(ks * 9 + i) * 18 + px] =
          (unsigned int)f2h(v[2*i]) | ((unsigned int)f2h(v[2*i+1]) << 16);
    }
    __syncthreads();
    // ---- MFMA: 9 ksteps of 32 over this chunk
    if (!KSPLIT || ((ci >> 2) == (w >> 1))){
      const bf16* arow = wb + (mw * 16 + lm) * 2304 + ci * 288 + lq * 8;
      #pragma unroll
      for (int kk = 0; kk < 288; kk += 32){
        short8 bfr = ld8s(cols32 + (kk/2 + lq*4) * 18 + lm, 18);
        short8 afr = *(const short8*)(arow + kk);
        acc = __builtin_amdgcn_mfma_f32_16x16x32_bf16(afr, bfr, acc, 0, 0, 0);
      }
    }
  }
  if constexpr (KSPLIT){
    __syncthreads();
    float* red = (float*)cols32;
    if (w >= 2){
      #pragma unroll
      for (int r = 0; r < 4; r++) red[(w - 2) * 256 + l * 4 + r] = acc[r];
    }
    __syncthreads();
    if (w >= 2) return;
    #pragma unroll
    for (int r = 0; r < 4; r++) acc[r] += red[w * 256 + l * 4 + r];
  }
  const int pxg = y * 64 + px0 + lm;
  #pragma unroll
  for (int r = 0; r < 4; r++){
    const int co = mw * 16 + lq * 4 + r;
    if (co >= CO) continue;
    float v = acc[r] + cbv[co];
    if constexpr (EPI){
      float inv = gam[co] * rsqrtf(var[co] + 1e-5f);
      v = v * inv + (bet[co] - mea[co] * inv);
      v = v * sigf(v);
    }
    outp[(b * CO + co) * 4096 + pxg] = v;
  }
}

__global__ __launch_bounds__(256) void k_coff2(const void* x, const int* flagp,
    const bf16* woffb, const float* cb, float* offc){
  __shared__ __align__(16) unsigned int cols32[144 * 18];
  if (*flagp) conv3v3_body<float, true, false>((const float*)x, woffb, cb,
                  nullptr, nullptr, nullptr, nullptr, offc, 18, cols32);
  else        conv3v3_body<bf16, true, false>((const bf16*)x, woffb, cb,
                  nullptr, nullptr, nullptr, nullptr, offc, 18, cols32);
}

__global__ __launch_bounds__(256) void k_g12(const float* xdense,
    const bf16* wg1b, const float* cb, const float* gam, const float* bet,
    const float* mea, const float* var, float* abuf){
  __shared__ __align__(16) unsigned int cols32[144 * 18];
  conv3v3_body<float, false, true>(xdense, wg1b, cb, gam, bet, mea, var,
                                   abuf, 64, cols32);
}

// ---------------------------------------------------------------------------
// K2a: deform gather -> global cols (per group). Block = 256 px strip x
// 4 channels. grid (64, 16). No LDS, no barriers: full latency hiding.
// colsg layout: [cl*9+tap][b*4096+px] u16 (rows of 16384, coalesced writes).
// ---------------------------------------------------------------------------
template<typename T>
__device__ __forceinline__ void dgath_body(const T* __restrict__ x,
    const float* __restrict__ offc, int g, unsigned short* __restrict__ colsg){
  const int strip = blockIdx.x, cs = blockIdx.y;
  const int b = strip >> 4;
  const int p = (strip & 15) * 256 + threadIdx.x;
  const int pg = b * 4096 + p;
  const int y = p >> 6, xx = p & 63;
  const float* ob = offc + b * 18 * 4096 + p;
  const T* xgb = x + (b * 256 + g * 64 + cs * 4) * 4096;
  #pragma unroll
  for (int tap = 0; tap < 9; tap++){
    float dy = ob[(2*tap)*4096], dx = ob[(2*tap+1)*4096];
    float py  = (float)(y + tap/3 - 1) + dy;
    float pxf = (float)(xx + tap%3 - 1) + dx;
    float y0f = floorf(py), x0f = floorf(pxf);
    int y0 = (int)y0f, x0 = (int)x0f;
    float wy1 = py - y0f, wx1 = pxf - x0f;
    float wy0 = 1.f - wy1, wx0 = 1.f - wx1;
    bool vy0 = (unsigned)y0 < 64u, vy1 = (unsigned)(y0+1) < 64u;
    bool vx0 = (unsigned)x0 < 64u, vx1 = (unsigned)(x0+1) < 64u;
    float w00 = (vy0 && vx0) ? wy0*wx0 : 0.f;
    float w01 = (vy0 && vx1) ? wy0*wx1 : 0.f;
    float w10 = (vy1 && vx0) ? wy1*wx0 : 0.f;
    float w11 = (vy1 && vx1) ? wy1*wx1 : 0.f;
    int yc0 = min(max(y0,0),63),   yc1 = min(max(y0+1,0),63);
    int xc0 = min(max(x0,0),63),   xc1 = min(max(x0+1,0),63);
    int i00 = yc0*64+xc0, i01 = yc0*64+xc1, i10 = yc1*64+xc0, i11 = yc1*64+xc1;
    #pragma unroll
    for (int c = 0; c < 4; c++){
      const T* xc = xgb + c * 4096;
      float val = w00*ldv(xc,i00) + w01*ldv(xc,i01)
                + w10*ldv(xc,i10) + w11*ldv(xc,i11);
      colsg[((cs*4 + c)*9 + tap)*16384 + pg] = f2h(val);
    }
  }
}

__global__ __launch_bounds__(256) void k_dgath(const void* x, const int* flagp,
    const float* offc, int g, unsigned short* colsg){
  if (*flagp) dgath_body((const float*)x, offc, g, colsg);
  else        dgath_body((const bf16*)x, offc, g, colsg);
}

// ---------------------------------------------------------------------------
// K2b: deform GEMM (per group): M=64 co, N=16384 px, K=576.
// Block = 16 px x 64 co, grid 1024. B staged k-pair u32 [k2][18] (2.3 KB).
// wave = m-tile; 18 MFMA/wave.
// ---------------------------------------------------------------------------
__global__ __launch_bounds__(256) void k_dgemm(const unsigned short* __restrict__ colsg,
    const bf16* __restrict__ wdefb, int g, unsigned short* __restrict__ xdirb){
  __shared__ __align__(16) unsigned int bt[32 * 18];
  const int n0 = blockIdx.x * 16;
  const int b = n0 >> 12, p0 = n0 & 4095;
  const int t = threadIdx.x;
  const int w = t >> 6, l = t & 63, lm = l & 15, lhi = l >> 4;
  const int spx = t & 15, skw = t >> 4;
  f32x4 acc = {0.f, 0.f, 0.f, 0.f};
  for (int ch = 0; ch < 9; ch++){
    __syncthreads();
    #pragma unroll
    for (int i = 0; i < 2; i++){
      const int k2l = skw * 2 + i;
      const int k = ch * 64 + 2 * k2l;
      unsigned int h0 = colsg[k * 16384 + n0 + spx];
      unsigned int h1 = colsg[(k + 1) * 16384 + n0 + spx];
      bt[k2l * 18 + spx] = h0 | (h1 << 16);
    }
    __syncthreads();
    #pragma unroll
    for (int ks = 0; ks < 2; ks++){
      short8 bfr = ld8s(bt + (ks*16 + lhi*4) * 18 + lm, 18);
      short8 afr = *(const short8*)(wdefb + (g*64 + w*16 + lm)*576
                                    + ch*64 + ks*32 + lhi*8);
      acc = __builtin_amdgcn_mfma_f32_16x16x32_bf16(afr, bfr, acc, 0, 0, 0);
    }
  }
  const int px = p0 + lm;
  #pragma unroll
  for (int r = 0; r < 4; r++)
    xdirb[(b*256 + g*64 + w*16 + lhi*4 + r)*4096 + px] = f2h(acc[r]);
}

// ---------------------------------------------------------------------------
// K3: 1x1 conv concat([x_dir, x_prev]) * w_cross — MFMA GEMM.
// Block = 64 px x 64 co, grid (256, 4). B staged k-pair u32 [k2][66] (8.4 KB,
// uniform 2-way banks).
// ---------------------------------------------------------------------------
template<typename T>
__device__ __forceinline__ void cross_body(const unsigned short* __restrict__ xdirb,
    const T* __restrict__ xprev, const bf16* __restrict__ wcb,
    float* __restrict__ xdense, unsigned int* bt){
  const int bx = blockIdx.x;
  const int b = bx >> 6, p0 = (bx & 63) * 64;
  const int co0 = blockIdx.y * 64;
  const int t = threadIdx.x;
  const int w = t >> 6, l = t & 63, lm = l & 15, lq = l >> 4;
  const int spx = t & 63, skw = t >> 6;
  f32x4 acc[4];
  #pragma unroll
  for (int m = 0; m < 4; m++) acc[m] = (f32x4){0.f,0.f,0.f,0.f};
  for (int cc = 0; cc < 512; cc += 64){
    __syncthreads();
    #pragma unroll
    for (int i = 0; i < 8; i++){
      const int k2l = skw * 8 + i;
      const int k = cc + 2 * k2l;
      unsigned int h0, h1;
      if (k < 256){
        h0 = xdirb[(b*256 + k)*4096 + p0 + spx];
        h1 = xdirb[(b*256 + k + 1)*4096 + p0 + spx];
      } else {
        h0 = ldh(xprev, (b*256 + k - 256)*4096 + p0 + spx);
        h1 = ldh(xprev, (b*256 + k - 255)*4096 + p0 + spx);
      }
      bt[k2l * 66 + spx] = h0 | (h1 << 16);
    }
    __syncthreads();
    #pragma unroll
    for (int ks = 0; ks < 2; ks++){
      short8 bfr = ld8s(bt + (ks*16 + lq*4) * 66 + w*16 + lm, 66);
      #pragma unroll
      for (int m = 0; m < 4; m++){
        short8 afr = *(const short8*)(wcb + (co0 + m*16 + lm)*512 + cc + ks*32 + lq*8);
        acc[m] = __builtin_amdgcn_mfma_f32_16x16x32_bf16(afr, bfr, acc[m], 0, 0, 0);
      }
    }
  }
  const int px = p0 + w*16 + lm;
  #pragma unroll
  for (int m = 0; m < 4; m++){
    #pragma unroll
    for (int r = 0; r < 4; r++)
      xdense[(b*256 + co0 + m*16 + lq*4 + r)*4096 + px] = acc[m][r];
  }
}

__global__ __launch_bounds__(256) void k_cross_m(const unsigned short* xdirb,
    const void* xprev, const int* flagp, const bf16* wcb, float* xdense){
  __shared__ __align__(16) unsigned int bt[32 * 66];
  if (*flagp) cross_body(xdirb, (const float*)xprev, wcb, xdense, bt);
  else        cross_body(xdirb, (const bf16*)xprev, wcb, xdense, bt);
}

// ---------------------------------------------------------------------------
// K5: 1x1 conv 64->256 + bias + sigmoid, xab = bf16(xdense * attn).
// grid (64, 16): 16 co per block (4x less abuf re-read than 4-co version).
// ---------------------------------------------------------------------------
__global__ __launch_bounds__(256) void k_attn(
    const float* __restrict__ abuf, const float* __restrict__ cw,
    const float* __restrict__ cb, const float* __restrict__ xdense,
    unsigned short* __restrict__ xab){
  const int q0 = blockIdx.x * 256;
  const int b = q0 >> 12, p0 = q0 & 4095;
  const int co0 = blockIdx.y * 16;
  const int p = p0 + threadIdx.x;
  float acc[16];
  #pragma unroll
  for (int j = 0; j < 16; j++) acc[j] = 0.f;
  const float* ab = abuf + b * 64 * 4096;
  for (int c = 0; c < 64; c++){
    float av = ab[c * 4096 + p];
    #pragma unroll
    for (int j = 0; j < 16; j++) acc[j] += cw[(co0 + j) * 64 + c] * av;
  }
  #pragma unroll
  for (int j = 0; j < 16; j++){
    const int co = co0 + j;
    float attn = sigf(acc[j] + cb[co]);
    const int idx = (b * 256 + co) * 4096 + p;
    xab[idx] = f2h(xdense[idx] * attn);
  }
}

// ---------------------------------------------------------------------------
// K6: 1x1 conv 256->256 — MFMA GEMM + bias + BN + SiLU + residual (dual).
// Same skeleton as cross, K=256, B from xab (bf16), k-pair LDS layout.
// ---------------------------------------------------------------------------
template<typename T>
__device__ __forceinline__ void out_body(const unsigned short* __restrict__ xab,
    const bf16* __restrict__ wob, const float* __restrict__ cb,
    const float* __restrict__ gam, const float* __restrict__ bet,
    const float* __restrict__ mea, const float* __restrict__ var,
    const T* __restrict__ xres, T* __restrict__ out, unsigned int* bt){
  const int bx = blockIdx.x;
  const int b = bx >> 6, p0 = (bx & 63) * 64;
  const int co0 = blockIdx.y * 64;
  const int t = threadIdx.x;
  const int w = t >> 6, l = t & 63, lm = l & 15, lq = l >> 4;
  const int spx = t & 63, skw = t >> 6;
  f32x4 acc[4];
  #pragma unroll
  for (int m = 0; m < 4; m++) acc[m] = (f32x4){0.f,0.f,0.f,0.f};
  for (int cc = 0; cc < 256; cc += 64){
    __syncthreads();
    #pragma unroll
    for (int i = 0; i < 8; i++){
      const int k2l = skw * 8 + i;
      const int k = cc + 2 * k2l;
      unsigned int h0 = xab[(b*256 + k)*4096 + p0 + spx];
      unsigned int h1 = xab[(b*256 + k + 1)*4096 + p0 + spx];
      bt[k2l * 66 + spx] = h0 | (h1 << 16);
    }
    __syncthreads();
    #pragma unroll
    for (int ks = 0; ks < 2; ks++){
      short8 bfr = ld8s(bt + (ks*16 + lq*4) * 66 + w*16 + lm, 66);
      #pragma unroll
      for (int m = 0; m < 4; m++){
        short8 afr = *(const short8*)(wob + (co0 + m*16 + lm)*256 + cc + ks*32 + lq*8);
        acc[m] = __builtin_amdgcn_mfma_f32_16x16x32_bf16(afr, bfr, acc[m], 0, 0, 0);
      }
    }
  }
  const int px = p0 + w*16 + lm;
  #pragma unroll
  for (int m = 0; m < 4; m++){
    #pragma unroll
    for (int r = 0; r < 4; r++){
      const int co = co0 + m*16 + lq*4 + r;
      float v = acc[m][r] + cb[co];
      float inv = gam[co] * rsqrtf(var[co] + 1e-5f);
      v = v * inv + (bet[co] - mea[co] * inv);
      v = v * sigf(v);
      const int idx = (b*256 + co)*4096 + px;
      stv(out, idx, v + ldv(xres, idx));
    }
  }
}

__global__ __launch_bounds__(256) void k_out_m(const unsigned short* xab,
    const bf16* wob, const float* cb, const float* gam, const float* bet,
    const float* mea, const float* var, const void* xres, void* out,
    const int* flagp){
  __shared__ __align__(16) unsigned int bt[32 * 66];
  if (*flagp) out_body(xab, wob, cb, gam, bet, mea, var, (const float*)xres, (float*)out, bt);
  else        out_body(xab, wob, cb, gam, bet, mea, var, (const bf16*)xres, (bf16*)out, bt);
}

// ---------------------------------------------------------------------------
extern "C" void kernel_launch(void* const* d_in, const int* in_sizes, int n_in,
                              void* d_out, int out_size, void* d_ws, size_t ws_size,
                              hipStream_t stream) {
  const void* x      = d_in[0];
  const void* x_prev = d_in[1];

  float* ws   = (float*)d_ws;
  int*   flag = (int*)ws;                 // ws[0..15] reserved
  float* cpar = ws + 16;                  // canonical fp32 params (551264 f)
  float* cb_off   = cpar + 41472;
  float* cb_g1    = cpar + 467488;
  float* cg1_gam  = cpar + 467552;
  float* cg1_bet  = cpar + 467616;
  float* cg1_mea  = cpar + 467680;
  float* cg1_var  = cpar + 467744;
  float* cw_g2    = cpar + 467808;
  float* cb_g2    = cpar + 484192;
  float* cb_out   = cpar + 549984;
  float* co_gam   = cpar + 550240;
  float* co_bet   = cpar + 550496;
  float* co_mea   = cpar + 550752;
  float* co_var   = cpar + 551008;

  float* q = ws + 16 + 551264;
  bf16*  wdefb   = (bf16*)q;  q += 73728;   // 147456 bf16
  bf16*  woffb   = (bf16*)q;  q += 36864;   // 73728 bf16 (18->32 pad)
  bf16*  wg1b    = (bf16*)q;  q += 73728;   // 147456 bf16
  bf16*  wcrossb = (bf16*)q;  q += 65536;   // 131072 bf16
  bf16*  woutb   = (bf16*)q;  q += 32768;   // 65536 bf16
  float* offc    = q;         q += 294912;  // 4*18*4096 f32
  unsigned short* xdirb = (unsigned short*)q; q += 2097152; // 4*256*4096 bf16
  float* xdense  = q;         q += 4194304; // 4*256*4096 f32
  float* abuf    = q;         q += 1048576; // 4*64*4096 f32
  unsigned short* xab = xdirb;              // reuse (xdirb dead after cross)
  // colsg (per-group deform cols, 576*16384 u16 = 18.9 MB) aliases
  // xdense+abuf (21 MB), which are dead until k_cross_m / k_g12.
  unsigned short* colsg = (unsigned short*)xdense;

  ParamSrc ps;
  for (int i = 0; i < 18; i++) ps.p[i] = d_in[2 + i];

  k_detect<<<dim3(1), 256, 0, stream>>>((const unsigned short*)x, flag);
  k_convert<<<dim3(96, 23), 256, 0, stream>>>(ps, flag, cpar, wdefb, woffb,
                                              wg1b, wcrossb, woutb);
  k_coff2<<<dim3(1024), 256, 0, stream>>>(x, flag, woffb, cb_off, offc);
  for (int g = 0; g < 4; g++){
    k_dgath<<<dim3(64, 16), 256, 0, stream>>>(x, flag, offc, g, colsg);
    k_dgemm<<<dim3(1024), 256, 0, stream>>>(colsg, wdefb, g, xdirb);
  }
  k_cross_m<<<dim3(256, 4), 256, 0, stream>>>(xdirb, x_prev, flag, wcrossb, xdense);
  k_g12<<<dim3(1024), 256, 0, stream>>>(xdense, wg1b, cb_g1, cg1_gam, cg1_bet,
                                        cg1_mea, cg1_var, abuf);
  k_attn<<<dim3(64, 16), 256, 0, stream>>>(abuf, cw_g2, cb_g2, xdense, xab);
  k_out_m<<<dim3(256, 4), 256, 0, stream>>>(xab, woutb, cb_out, co_gam, co_bet,
                                            co_mea, co_var, x, d_out, flag);
}